// Round 13
// baseline (1947.693 us; speedup 1.0000x reference)
//
#include <hip/hip_runtime.h>
#include <hip/hip_bf16.h>

#define NL 8
#define NV 50257
#define NC 1024
#define NH 16
#define NT 1024
#define NFF 4096
#define NB 2
#define NM (NB*NT)   // 2048 rows

typedef __attribute__((ext_vector_type(8))) short bf16x8;
typedef __attribute__((ext_vector_type(4))) float f32x4;

__device__ __forceinline__ unsigned short f2bf(float f) {
    union { float f; unsigned u; } a; a.f = f;
    unsigned r = a.u + 0x7FFFu + ((a.u >> 16) & 1u);
    return (unsigned short)(r >> 16);
}

__device__ __forceinline__ void gload16(const unsigned short* g, unsigned short* l) {
    __builtin_amdgcn_global_load_lds(
        (const __attribute__((address_space(1))) unsigned int*)g,
        (__attribute__((address_space(3))) unsigned int*)l,
        16, 0, 0);
}

template<int VN> __device__ __forceinline__ void vwait() {
    asm volatile("s_waitcnt vmcnt(%0)" :: "n"(VN) : "memory");
}
__device__ __forceinline__ void barrier_mem() {
    asm volatile("" ::: "memory");
    __builtin_amdgcn_s_barrier();
    asm volatile("" ::: "memory");
}

// ---------------- embedding: x[b,t,:] = tok_emb[idx[b,t],:] + pos_emb[t,:]
__global__ __launch_bounds__(256) void embed_kernel(
    const int* __restrict__ idx, const float* __restrict__ te,
    const float* __restrict__ pe, float* __restrict__ x) {
    int row = blockIdx.x;
    int t = row & (NT - 1);
    int id = idx[row];
    const float4 a = reinterpret_cast<const float4*>(te + (size_t)id * NC)[threadIdx.x];
    const float4 b = reinterpret_cast<const float4*>(pe + (size_t)t * NC)[threadIdx.x];
    float4 o; o.x = a.x + b.x; o.y = a.y + b.y; o.z = a.z + b.z; o.w = a.w + b.w;
    reinterpret_cast<float4*>(x + (size_t)row * NC)[threadIdx.x] = o;
}

// ---------------- f32 -> bf16 bulk convert (tok_emb)
__global__ __launch_bounds__(256) void cvt_bf16_kernel(
    const float* __restrict__ in, unsigned short* __restrict__ out, size_t n4) {
    size_t i = (size_t)blockIdx.x * 256 + threadIdx.x;
    if (i >= n4) return;
    float4 v = reinterpret_cast<const float4*>(in)[i];
    uint2 u;
    u.x = (unsigned)f2bf(v.x) | ((unsigned)f2bf(v.y) << 16);
    u.y = (unsigned)f2bf(v.z) | ((unsigned)f2bf(v.w) << 16);
    reinterpret_cast<uint2*>(out)[i] = u;
}

// ---------------- fused weight transpose+convert for one layer (4 matrices)
__global__ __launch_bounds__(256) void wtrans4_kernel(
    const float* __restrict__ s0, const float* __restrict__ s1,
    const float* __restrict__ s2, const float* __restrict__ s3,
    unsigned short* __restrict__ d0, unsigned short* __restrict__ d1,
    unsigned short* __restrict__ d2, unsigned short* __restrict__ d3) {
    __shared__ float tile[32][33];
    int bid = blockIdx.x;
    const float* W; unsigned short* D; int K, N, tn, tk;
    if (bid < 3072)      { W = s0; D = d0; K = 1024; N = 3072; tn = bid % 96;  tk = bid / 96; }
    else if (bid < 4096) { int t = bid - 3072; W = s1; D = d1; K = 1024; N = 1024; tn = t & 31;  tk = t >> 5; }
    else if (bid < 8192) { int t = bid - 4096; W = s2; D = d2; K = 1024; N = 4096; tn = t & 127; tk = t >> 7; }
    else                 { int t = bid - 8192; W = s3; D = d3; K = 4096; N = 1024; tn = t & 31;  tk = t >> 5; }
    int n0 = tn * 32, k0 = tk * 32;
    int tx = threadIdx.x, ty = threadIdx.y;  // (32,8)
#pragma unroll
    for (int i = 0; i < 4; ++i)
        tile[ty + i * 8][tx] = W[(size_t)(k0 + ty + i * 8) * N + n0 + tx];
    __syncthreads();
#pragma unroll
    for (int i = 0; i < 4; ++i)
        D[(size_t)(n0 + ty + i * 8) * K + k0 + tx] = f2bf(tile[tx][ty + i * 8]);
}

// ---------------- layernorm (f32 in -> bf16 out), one block per row, C=1024
__global__ __launch_bounds__(256) void ln_kernel(
    const float* __restrict__ x, const float* __restrict__ gam,
    const float* __restrict__ bet, unsigned short* __restrict__ out) {
    __shared__ float red[4];
    int row = blockIdx.x, tid = threadIdx.x;
    const float4 v = reinterpret_cast<const float4*>(x + (size_t)row * NC)[tid];
    float s = v.x + v.y + v.z + v.w;
#pragma unroll
    for (int m = 32; m >= 1; m >>= 1) s += __shfl_xor(s, m, 64);
    if ((tid & 63) == 0) red[tid >> 6] = s;
    __syncthreads();
    float mean = (red[0] + red[1] + red[2] + red[3]) * (1.0f / NC);
    __syncthreads();
    float dx = v.x - mean, dy = v.y - mean, dz = v.z - mean, dw = v.w - mean;
    float q = dx * dx + dy * dy + dz * dz + dw * dw;
#pragma unroll
    for (int m = 32; m >= 1; m >>= 1) q += __shfl_xor(q, m, 64);
    if ((tid & 63) == 0) red[tid >> 6] = q;
    __syncthreads();
    float var = (red[0] + red[1] + red[2] + red[3]) * (1.0f / NC);
    float rstd = rsqrtf(var + 1e-5f);
    int c = tid * 4;
    const float4 g4 = reinterpret_cast<const float4*>(gam)[tid];
    const float4 b4 = reinterpret_cast<const float4*>(bet)[tid];
    uint2 u;
    u.x = (unsigned)f2bf(dx * rstd * g4.x + b4.x) |
          ((unsigned)f2bf(dy * rstd * g4.y + b4.y) << 16);
    u.y = (unsigned)f2bf(dz * rstd * g4.z + b4.z) |
          ((unsigned)f2bf(dw * rstd * g4.w + b4.w) << 16);
    reinterpret_cast<uint2*>(out + (size_t)row * NC + c)[0] = u;
}

// ---------------- GEMM: 128x128 tile, 3-buffer ring, counted vmcnt. (proj)
template<int ACT, bool BIAS, bool OUTBF16, bool ATOMIC>
__global__ __launch_bounds__(256) void gemm_kernel(
    const unsigned short* __restrict__ A, const unsigned short* __restrict__ Bt,
    const float* __restrict__ bias, void* __restrict__ Cout,
    int N, int K, int ldc, int ksub) {
    __shared__ unsigned short lds[3][2][128 * 32];
    const int tid = threadIdx.x;
    const int lane = tid & 63;
    const int wave = tid >> 6;
    const int wm = wave >> 1, wn = wave & 1;
    const int lr = lane & 15, lg = lane >> 4;
    const int m0 = blockIdx.x * 128, n0 = blockIdx.y * 128;
    const int kbeg = blockIdx.z * ksub;

    const int r0 = tid >> 2;
    const int c0 = (tid & 3) * 8;
    const unsigned short* Ag0 = A + (size_t)(m0 + r0) * K + c0;
    const unsigned short* Ag1 = A + (size_t)(m0 + r0 + 64) * K + c0;
    const unsigned short* Bg0 = Bt + (size_t)(n0 + r0) * K + c0;
    const unsigned short* Bg1 = Bt + (size_t)(n0 + r0 + 64) * K + c0;
    const int dw0 = wave * 512;
    const int dw1 = 2048 + wave * 512;

    const f32x4 zero4 = {0.0f, 0.0f, 0.0f, 0.0f};
    f32x4 acc[4][4];
#pragma unroll
    for (int i = 0; i < 4; ++i)
#pragma unroll
        for (int j = 0; j < 4; ++j) acc[i][j] = zero4;

    auto stage = [&](int buf, int k0) {
        gload16(Ag0 + k0, &lds[buf][0][dw0]);
        gload16(Ag1 + k0, &lds[buf][0][dw1]);
        gload16(Bg0 + k0, &lds[buf][1][dw0]);
        gload16(Bg1 + k0, &lds[buf][1][dw1]);
    };

    const int nt = ksub >> 5;
    stage(0, kbeg);
    stage(1, kbeg + 32);
    vwait<4>();
    barrier_mem();
    int b0 = 0, b1 = 1, b2 = 2;
    for (int t = 0; t < nt; ++t) {
        const bool pf = (t + 2 < nt);
        if (pf) stage(b2, kbeg + (t + 2) * 32);
        bf16x8 af[4], bfr[4];
#pragma unroll
        for (int f = 0; f < 4; ++f) {
            af[f]  = *reinterpret_cast<const bf16x8*>(&lds[b0][0][(wm * 64 + f * 16 + lr) * 32 + lg * 8]);
            bfr[f] = *reinterpret_cast<const bf16x8*>(&lds[b0][1][(wn * 64 + f * 16 + lr) * 32 + lg * 8]);
        }
#pragma unroll
        for (int i = 0; i < 4; ++i)
#pragma unroll
            for (int j = 0; j < 4; ++j)
                acc[i][j] = __builtin_amdgcn_mfma_f32_16x16x32_bf16(af[i], bfr[j], acc[i][j], 0, 0, 0);
        if (t + 1 < nt) {
            if (pf) vwait<4>(); else vwait<0>();
            barrier_mem();
        }
        int tmp = b0; b0 = b1; b1 = b2; b2 = tmp;
    }

#pragma unroll
    for (int i = 0; i < 4; ++i) {
#pragma unroll
        for (int j = 0; j < 4; ++j) {
            int col = n0 + wn * 64 + j * 16 + lr;
            float bv = (BIAS && kbeg == 0) ? bias[col] : 0.0f;
#pragma unroll
            for (int r = 0; r < 4; ++r) {
                int row = m0 + wm * 64 + i * 16 + lg * 4 + r;
                float v = acc[i][j][r] + bv;
                if (ACT == 1) v = 0.5f * v * (1.0f + erff(v * 0.70710678118654752f));
                if (ATOMIC) {
                    atomicAdd(reinterpret_cast<float*>(Cout) + (size_t)row * ldc + col, v);
                } else if (OUTBF16) {
                    reinterpret_cast<unsigned short*>(Cout)[(size_t)row * ldc + col] = f2bf(v);
                } else {
                    reinterpret_cast<float*>(Cout)[(size_t)row * ldc + col] = v;
                }
            }
        }
    }
}

// ---------------- 256-wide GEMM (128x256): 2-slot 48KB ring -> 3 blocks/CU.
// stage(t+1) issued BEFORE compute(t); vwait(0)+barrier after compute so the
// load latency hides under the 16-MFMA cluster (m97/m114 occupancy overlap).
template<int ACT, bool BIAS, bool OUTBF16, bool NEDGE, bool ATOMIC>
__global__ __launch_bounds__(512, 4) void gemm256_kernel(
    const unsigned short* __restrict__ A, const unsigned short* __restrict__ Bt,
    const float* __restrict__ bias, void* __restrict__ Cout,
    int N, int K, int ldc, int ksub) {
    __shared__ unsigned short lds[2][12288];   // slot: A[128][32] (8KB) + B[256][32] (16KB)
    const int tid = threadIdx.x;
    const int lane = tid & 63, wid = tid >> 6;
    const int wm = wid >> 2, wn = wid & 3;
    const int lr = lane & 15, lg = lane >> 4;

    const int qx = gridDim.x >> 3;
    const int orig = blockIdx.x;
    const int wg = (orig & 7) * qx + (orig >> 3);
    const int m0 = (wg & 15) * 128;
    const int n0 = (wg >> 4) * 256;
    const int kbeg2 = blockIdx.y * ksub * 2;

    int rA, kA;
    { int pr = tid >> 3, s = tid & 7; int li = s ^ (pr & 7);
      rA = 2 * pr + (li >> 2); kA = (li & 3) << 4; }
    int rB1, kB1;
    { int o = tid + 512; int pr = o >> 3, s = o & 7; int li = s ^ (pr & 7);
      rB1 = 2 * pr + (li >> 2); kB1 = (li & 3) << 4; }
    int nrow0 = n0 + rA, nrow1 = n0 + rB1;
    if (NEDGE) { nrow0 = min(nrow0, N - 1); nrow1 = min(nrow1, N - 1); }
    const char* pAg  = (const char*)A  + (size_t)(m0 + rA) * (2 * K) + kA + kbeg2;
    const char* pBg0 = (const char*)Bt + (size_t)nrow0 * (2 * K) + kA + kbeg2;
    const char* pBg1 = (const char*)Bt + (size_t)nrow1 * (2 * K) + kB1 + kbeg2;
    const int dst = wid * 512;

    const int swz = (((lr & 1) << 6) | (lg << 4)) ^ (((lr >> 1) & 7) << 4);
    const int pbA = (wm * 32 + (lr >> 1)) * 128 + swz;
    const int pbB = (wn * 32 + (lr >> 1)) * 128 + swz;

    const f32x4 zero4 = {0.0f, 0.0f, 0.0f, 0.0f};
    f32x4 acc[4][4];
#pragma unroll
    for (int i = 0; i < 4; ++i)
#pragma unroll
        for (int j = 0; j < 4; ++j) acc[i][j] = zero4;

    auto stage2 = [&](int slot, int koff) {
        unsigned short* base = &lds[slot][0];
        gload16((const unsigned short*)(pAg  + koff), base + dst);
        gload16((const unsigned short*)(pBg0 + koff), base + 4096 + dst);
        gload16((const unsigned short*)(pBg1 + koff), base + 8192 + dst);
    };
    auto rdA = [&](int slot, int mf) -> bf16x8 {
        return *reinterpret_cast<const bf16x8*>(
            (const char*)&lds[slot][0] + pbA + mf * 1024);
    };
    auto rdB = [&](int slot, int nf) -> bf16x8 {
        return *reinterpret_cast<const bf16x8*>(
            (const char*)&lds[slot][0] + 8192 + pbB + nf * 1024);
    };

    const int nt = ksub >> 5;
    stage2(0, 0);
    vwait<0>();
    barrier_mem();
    for (int t = 0; t < nt; ++t) {
        const int cur = t & 1;
        if (t + 1 < nt) stage2(cur ^ 1, (t + 1) * 64);   // prefetch before compute
        bf16x8 bf0 = rdB(cur, 0), bf1 = rdB(cur, 1), bf2 = rdB(cur, 2), bf3 = rdB(cur, 3);
        bf16x8 a0 = rdA(cur, 0), a1 = rdA(cur, 1), a2 = rdA(cur, 2), a3 = rdA(cur, 3);
        __builtin_amdgcn_s_setprio(1);
        acc[0][0] = __builtin_amdgcn_mfma_f32_16x16x32_bf16(a0, bf0, acc[0][0], 0, 0, 0);
        acc[0][1] = __builtin_amdgcn_mfma_f32_16x16x32_bf16(a0, bf1, acc[0][1], 0, 0, 0);
        acc[0][2] = __builtin_amdgcn_mfma_f32_16x16x32_bf16(a0, bf2, acc[0][2], 0, 0, 0);
        acc[0][3] = __builtin_amdgcn_mfma_f32_16x16x32_bf16(a0, bf3, acc[0][3], 0, 0, 0);
        acc[1][0] = __builtin_amdgcn_mfma_f32_16x16x32_bf16(a1, bf0, acc[1][0], 0, 0, 0);
        acc[1][1] = __builtin_amdgcn_mfma_f32_16x16x32_bf16(a1, bf1, acc[1][1], 0, 0, 0);
        acc[1][2] = __builtin_amdgcn_mfma_f32_16x16x32_bf16(a1, bf2, acc[1][2], 0, 0, 0);
        acc[1][3] = __builtin_amdgcn_mfma_f32_16x16x32_bf16(a1, bf3, acc[1][3], 0, 0, 0);
        acc[2][0] = __builtin_amdgcn_mfma_f32_16x16x32_bf16(a2, bf0, acc[2][0], 0, 0, 0);
        acc[2][1] = __builtin_amdgcn_mfma_f32_16x16x32_bf16(a2, bf1, acc[2][1], 0, 0, 0);
        acc[2][2] = __builtin_amdgcn_mfma_f32_16x16x32_bf16(a2, bf2, acc[2][2], 0, 0, 0);
        acc[2][3] = __builtin_amdgcn_mfma_f32_16x16x32_bf16(a2, bf3, acc[2][3], 0, 0, 0);
        acc[3][0] = __builtin_amdgcn_mfma_f32_16x16x32_bf16(a3, bf0, acc[3][0], 0, 0, 0);
        acc[3][1] = __builtin_amdgcn_mfma_f32_16x16x32_bf16(a3, bf1, acc[3][1], 0, 0, 0);
        acc[3][2] = __builtin_amdgcn_mfma_f32_16x16x32_bf16(a3, bf2, acc[3][2], 0, 0, 0);
        acc[3][3] = __builtin_amdgcn_mfma_f32_16x16x32_bf16(a3, bf3, acc[3][3], 0, 0, 0);
        __builtin_amdgcn_s_setprio(0);
        if (t + 1 < nt) {
            vwait<0>();        // prefetch (issued pre-compute) has landed
            barrier_mem();     // all waves' loads visible; WAR separated
        }
    }

#pragma unroll
    for (int mf = 0; mf < 4; ++mf)
#pragma unroll
        for (int nf = 0; nf < 4; ++nf) {
            int col = n0 + wn * 64 + nf * 16 + lr;
            if (NEDGE && col >= N) continue;
            float bv = (BIAS && blockIdx.y == 0) ? bias[col] : 0.0f;
#pragma unroll
            for (int r = 0; r < 4; ++r) {
                int row = m0 + wm * 64 + mf * 16 + lg * 4 + r;
                float v = acc[mf][nf][r] + bv;
                if (ACT == 1) v = 0.5f * v * (1.0f + erff(v * 0.70710678118654752f));
                if (ATOMIC)
                    atomicAdd(reinterpret_cast<float*>(Cout) + (size_t)row * ldc + col, v);
                else if (OUTBF16)
                    reinterpret_cast<unsigned short*>(Cout)[(size_t)row * ldc + col] = f2bf(v);
                else
                    reinterpret_cast<float*>(Cout)[(size_t)row * ldc + col] = v;
            }
        }
}

// ---------------- V transpose: qkv v-part [t][d] -> vt[b][h][d][t] (bf16)
__global__ __launch_bounds__(256) void vtrans_kernel(
    const unsigned short* __restrict__ qkv, unsigned short* __restrict__ vt) {
    __shared__ unsigned short tile[32][33];
    int bh = blockIdx.z; int b = bh >> 4, h = bh & 15;
    int t0 = blockIdx.x * 32, d0 = blockIdx.y * 32;
    int tx = threadIdx.x, ty = threadIdx.y;  // (32,8)
#pragma unroll
    for (int i = 0; i < 4; ++i)
        tile[ty + i * 8][tx] =
            qkv[(size_t)(b * NT + t0 + ty + i * 8) * 3072 + 2048 + h * 64 + d0 + tx];
    __syncthreads();
#pragma unroll
    for (int i = 0; i < 4; ++i)
        vt[((size_t)(b * NH + h) * 64 + d0 + ty + i * 8) * NT + t0 + tx] = tile[tx][ty + i * 8];
}

// ---------------- causal flash attention, split-K over key tiles (2 splits).
__global__ __launch_bounds__(64) void attn_kernel(
    const unsigned short* __restrict__ qkv, const unsigned short* __restrict__ vt,
    float* __restrict__ opart, float2* __restrict__ ml) {
    __shared__ unsigned short Vs[64][72];
    __shared__ unsigned short Ps[32][72];
    const int qt = blockIdx.x;
    const int h  = blockIdx.y;
    const int b  = blockIdx.z >> 1;
    const int sp = blockIdx.z & 1;
    const int lane = threadIdx.x;
    const int lr = lane & 15, lg = lane >> 4;

    const unsigned short* qbase = qkv + (size_t)(b * NT + qt * 32) * 3072 + h * 64;
    bf16x8 qf[2][2];
#pragma unroll
    for (int mf = 0; mf < 2; ++mf)
#pragma unroll
        for (int kc = 0; kc < 2; ++kc)
            qf[mf][kc] = *reinterpret_cast<const bf16x8*>(
                qbase + (size_t)(mf * 16 + lr) * 3072 + kc * 32 + lg * 8);

    const f32x4 zero4 = {0.0f, 0.0f, 0.0f, 0.0f};
    f32x4 oacc[2][4];
    float mrow[2][4], lsum[2][4];
#pragma unroll
    for (int mf = 0; mf < 2; ++mf) {
#pragma unroll
        for (int nf = 0; nf < 4; ++nf) oacc[mf][nf] = zero4;
#pragma unroll
        for (int r = 0; r < 4; ++r) { mrow[mf][r] = -INFINITY; lsum[mf][r] = 0.0f; }
    }

    const int qend = qt * 32 + 32;
    const int nkt = (qend + 63) >> 6;
    const int khalf = (nkt + 1) >> 1;
    const int kt0 = sp ? khalf : 0;
    const int kt1 = sp ? nkt : khalf;
    const unsigned short* kbase = qkv + (size_t)(b * NT) * 3072 + NC + h * 64;
    const unsigned short* vbase = vt + (size_t)((b * NH + h) * 64) * NT;

    for (int kt = kt0; kt < kt1; ++kt) {
        __syncthreads();
#pragma unroll
        for (int i = 0; i < 8; ++i) {
            int chunk = lane + i * 64;
            int d = chunk >> 3;
            int kk = (chunk & 7) * 8;
            *reinterpret_cast<bf16x8*>(&Vs[d][kk]) =
                *reinterpret_cast<const bf16x8*>(vbase + (size_t)d * NT + kt * 64 + kk);
        }
        f32x4 s[2][4];
#pragma unroll
        for (int mf = 0; mf < 2; ++mf)
#pragma unroll
            for (int jf = 0; jf < 4; ++jf) s[mf][jf] = zero4;
#pragma unroll
        for (int kc = 0; kc < 2; ++kc) {
            bf16x8 kf[4];
#pragma unroll
            for (int jf = 0; jf < 4; ++jf)
                kf[jf] = *reinterpret_cast<const bf16x8*>(
                    kbase + (size_t)(kt * 64 + jf * 16 + lr) * 3072 + kc * 32 + lg * 8);
#pragma unroll
            for (int mf = 0; mf < 2; ++mf)
#pragma unroll
                for (int jf = 0; jf < 4; ++jf)
                    s[mf][jf] = __builtin_amdgcn_mfma_f32_16x16x32_bf16(
                        qf[mf][kc], kf[jf], s[mf][jf], 0, 0, 0);
        }
        const bool lastt = (kt == nkt - 1);
#pragma unroll
        for (int mf = 0; mf < 2; ++mf) {
#pragma unroll
            for (int r = 0; r < 4; ++r) {
                int rowg = qt * 32 + mf * 16 + lg * 4 + r;
                float tmax = -INFINITY;
#pragma unroll
                for (int jf = 0; jf < 4; ++jf) {
                    float v = s[mf][jf][r] * 0.125f;
                    if (lastt) {
                        int colg = kt * 64 + jf * 16 + lr;
                        if (colg > rowg) v = -INFINITY;
                    }
                    s[mf][jf][r] = v;
                    tmax = fmaxf(tmax, v);
                }
                tmax = fmaxf(tmax, __shfl_xor(tmax, 1, 64));
                tmax = fmaxf(tmax, __shfl_xor(tmax, 2, 64));
                tmax = fmaxf(tmax, __shfl_xor(tmax, 4, 64));
                tmax = fmaxf(tmax, __shfl_xor(tmax, 8, 64));
                float mnew = fmaxf(mrow[mf][r], tmax);
                float corr = __expf(mrow[mf][r] - mnew);
                float ps = 0.0f;
#pragma unroll
                for (int jf = 0; jf < 4; ++jf) {
                    float p = __expf(s[mf][jf][r] - mnew);
                    s[mf][jf][r] = p;
                    ps += p;
                }
                ps += __shfl_xor(ps, 1, 64);
                ps += __shfl_xor(ps, 2, 64);
                ps += __shfl_xor(ps, 4, 64);
                ps += __shfl_xor(ps, 8, 64);
                lsum[mf][r] = lsum[mf][r] * corr + ps;
                mrow[mf][r] = mnew;
#pragma unroll
                for (int nf = 0; nf < 4; ++nf) oacc[mf][nf][r] *= corr;
            }
        }
#pragma unroll
        for (int mf = 0; mf < 2; ++mf)
#pragma unroll
            for (int jf = 0; jf < 4; ++jf)
#pragma unroll
                for (int r = 0; r < 4; ++r)
                    Ps[mf * 16 + lg * 4 + r][jf * 16 + lr] = f2bf(s[mf][jf][r]);
        __syncthreads();
#pragma unroll
        for (int kc = 0; kc < 2; ++kc) {
            bf16x8 pf[2], vf[4];
#pragma unroll
            for (int mf = 0; mf < 2; ++mf)
                pf[mf] = *reinterpret_cast<const bf16x8*>(&Ps[mf * 16 + lr][kc * 32 + lg * 8]);
#pragma unroll
            for (int nf = 0; nf < 4; ++nf)
                vf[nf] = *reinterpret_cast<const bf16x8*>(&Vs[nf * 16 + lr][kc * 32 + lg * 8]);
#pragma unroll
            for (int mf = 0; mf < 2; ++mf)
#pragma unroll
                for (int nf = 0; nf < 4; ++nf)
                    oacc[mf][nf] = __builtin_amdgcn_mfma_f32_16x16x32_bf16(
                        pf[mf], vf[nf], oacc[mf][nf], 0, 0, 0);
        }
    }

    const size_t rowbase = (size_t)sp * 2048 + b * NT + qt * 32;
    float* op = opart + rowbase * NC + h * 64;
#pragma unroll
    for (int mf = 0; mf < 2; ++mf)
#pragma unroll
        for (int nf = 0; nf < 4; ++nf)
#pragma unroll
            for (int r = 0; r < 4; ++r)
                op[(size_t)(mf * 16 + lg * 4 + r) * NC + nf * 16 + lr] = oacc[mf][nf][r];
    if (lr == 0) {
#pragma unroll
        for (int mf = 0; mf < 2; ++mf)
#pragma unroll
            for (int r = 0; r < 4; ++r)
                ml[(rowbase + mf * 16 + lg * 4 + r) * NH + h] =
                    make_float2(mrow[mf][r], lsum[mf][r]);
    }
}

// ---------------- combine 2 attention splits -> bf16 O
__global__ __launch_bounds__(256) void attn_combine_kernel(
    const float* __restrict__ opart, const float2* __restrict__ ml,
    unsigned short* __restrict__ o) {
    const int row = blockIdx.x;
    const int tid = threadIdx.x;
    const int h = tid >> 4;
    float2 a = ml[(size_t)row * NH + h];
    float2 c = ml[(size_t)(2048 + row) * NH + h];
    float m = fmaxf(a.x, c.x);
    float w0 = __expf(a.x - m), w1 = __expf(c.x - m);
    float inv = 1.0f / (a.y * w0 + c.y * w1);
    float4 o0 = reinterpret_cast<const float4*>(opart + (size_t)row * NC)[tid];
    float4 o1 = reinterpret_cast<const float4*>(opart + (size_t)(2048 + row) * NC)[tid];
    uint2 u;
    u.x = (unsigned)f2bf((o0.x * w0 + o1.x * w1) * inv) |
          ((unsigned)f2bf((o0.y * w0 + o1.y * w1) * inv) << 16);
    u.y = (unsigned)f2bf((o0.z * w0 + o1.z * w1) * inv) |
          ((unsigned)f2bf((o0.w * w0 + o1.w * w1) * inv) << 16);
    reinterpret_cast<uint2*>(o + (size_t)row * NC)[tid] = u;
}

extern "C" void kernel_launch(void* const* d_in, const int* in_sizes, int n_in,
                              void* d_out, int out_size, void* d_ws, size_t ws_size,
                              hipStream_t stream) {
    (void)in_sizes; (void)n_in; (void)out_size; (void)ws_size;
    const int*   idx    = (const int*)  d_in[0];
    const float* tok    = (const float*)d_in[1];
    const float* pos    = (const float*)d_in[2];
    const float* qkv_w  = (const float*)d_in[3];
    const float* qkv_b  = (const float*)d_in[4];
    const float* out_w  = (const float*)d_in[5];
    const float* out_b  = (const float*)d_in[6];
    const float* ln1_s  = (const float*)d_in[7];
    const float* ln1_b  = (const float*)d_in[8];
    const float* ln2_s  = (const float*)d_in[9];
    const float* ln2_b  = (const float*)d_in[10];
    const float* ffn_w1 = (const float*)d_in[11];
    const float* ffn_b1 = (const float*)d_in[12];
    const float* ffn_w2 = (const float*)d_in[13];
    const float* ffn_b2 = (const float*)d_in[14];
    const float* lnf_s  = (const float*)d_in[15];
    const float* lnf_b  = (const float*)d_in[16];

    char* p = (char*)d_ws;
    float* x              = (float*)p;          p += (size_t)NM * NC * 4;
    unsigned short* hbuf  = (unsigned short*)p; p += (size_t)NM * NC * 2;
    unsigned short* qkvb  = (unsigned short*)p; p += (size_t)NM * 3 * NC * 2;
    unsigned short* obuf  = (unsigned short*)p; p += (size_t)NM * NC * 2;
    unsigned short* gbuf  = (unsigned short*)p; p += (size_t)NM * NFF * 2;
    unsigned short* vtb   = (unsigned short*)p; p += (size_t)NB * NH * 64 * NT * 2;
    unsigned short* wq    = (unsigned short*)p; p += (size_t)3 * NC * NC * 2;
    unsigned short* wo    = (unsigned short*)p; p += (size_t)NC * NC * 2;
    unsigned short* w1    = (unsigned short*)p; p += (size_t)NC * NFF * 2;
    unsigned short* w2    = (unsigned short*)p; p += (size_t)NFF * NC * 2;
    unsigned short* temb  = (unsigned short*)p; p += (size_t)NV * NC * 2;
    float* opart          = (float*)p;          p += (size_t)2 * NM * NC * 4;
    float2* mlbuf         = (float2*)p;         p += (size_t)2 * NM * NH * 8;

    {
        size_t n4 = (size_t)NV * NC / 4;
        int blocks = (int)((n4 + 255) / 256);
        cvt_bf16_kernel<<<blocks, 256, 0, stream>>>(tok, temb, n4);
    }
    embed_kernel<<<NM, 256, 0, stream>>>(idx, tok, pos, x);

    for (int l = 0; l < NL; ++l) {
        wtrans4_kernel<<<12288, dim3(32, 8), 0, stream>>>(
            qkv_w + (size_t)l * NC * 3 * NC, out_w + (size_t)l * NC * NC,
            ffn_w1 + (size_t)l * NC * NFF, ffn_w2 + (size_t)l * NFF * NC,
            wq, wo, w1, w2);

        ln_kernel<<<NM, 256, 0, stream>>>(x, ln1_s + (size_t)l * NC, ln1_b + (size_t)l * NC, hbuf);
        gemm256_kernel<0, true, true, false, false><<<dim3(192), 512, 0, stream>>>(
            hbuf, wq, qkv_b + (size_t)l * 3 * NC, qkvb, 3 * NC, NC, 3 * NC, NC);
        vtrans_kernel<<<dim3(32, 2, 32), dim3(32, 8), 0, stream>>>(qkvb, vtb);
        attn_kernel<<<dim3(32, 16, 4), 64, 0, stream>>>(qkvb, vtb, opart, mlbuf);
        attn_combine_kernel<<<NM, 256, 0, stream>>>(opart, mlbuf, obuf);
        gemm_kernel<0, true, false, true><<<dim3(16, 8, 2), 256, 0, stream>>>(
            obuf, wo, out_b + (size_t)l * NC, x, NC, NC, NC, NC / 2);
        ln_kernel<<<NM, 256, 0, stream>>>(x, ln2_s + (size_t)l * NC, ln2_b + (size_t)l * NC, hbuf);
        gemm256_kernel<1, true, true, false, false><<<dim3(256), 512, 0, stream>>>(
            hbuf, w1, ffn_b1 + (size_t)l * NFF, gbuf, NFF, NC, NFF, NC);
        gemm256_kernel<0, true, false, false, true><<<dim3(64, 4), 512, 0, stream>>>(
            gbuf, w2, ffn_b2 + (size_t)l * NC, x, NC, NFF, NC, NFF / 4);
    }
    ln_kernel<<<NM, 256, 0, stream>>>(x, lnf_s, lnf_b, hbuf);
    // tied head: 128x256 tiles, grid = 16 M x 197 N = 3152 (%8==0)
    gemm256_kernel<0, false, false, true, false><<<dim3(16 * 197), 512, 0, stream>>>(
        hbuf, temb, nullptr, d_out, NV, NC, NV, NC);
}

// Round 14
// 1831.649 us; speedup vs baseline: 1.0634x; 1.0634x over previous
//
#include <hip/hip_runtime.h>
#include <hip/hip_bf16.h>

#define NL 8
#define NV 50257
#define NC 1024
#define NH 16
#define NT 1024
#define NFF 4096
#define NB 2
#define NM (NB*NT)   // 2048 rows

typedef __attribute__((ext_vector_type(8))) short bf16x8;
typedef __attribute__((ext_vector_type(4))) float f32x4;

__device__ __forceinline__ unsigned short f2bf(float f) {
    union { float f; unsigned u; } a; a.f = f;
    unsigned r = a.u + 0x7FFFu + ((a.u >> 16) & 1u);
    return (unsigned short)(r >> 16);
}
__device__ __forceinline__ float bf2f(unsigned short s) {
    union { unsigned u; float f; } a; a.u = (unsigned)s << 16;
    return a.f;
}

__device__ __forceinline__ void gload16(const unsigned short* g, unsigned short* l) {
    __builtin_amdgcn_global_load_lds(
        (const __attribute__((address_space(1))) unsigned int*)g,
        (__attribute__((address_space(3))) unsigned int*)l,
        16, 0, 0);
}

template<int VN> __device__ __forceinline__ void vwait() {
    asm volatile("s_waitcnt vmcnt(%0)" :: "n"(VN) : "memory");
}
__device__ __forceinline__ void barrier_mem() {
    asm volatile("" ::: "memory");
    __builtin_amdgcn_s_barrier();
    asm volatile("" ::: "memory");
}

// ---------------- embedding: x[b,t,:] = tok_emb[idx[b,t],:] + pos_emb[t,:]
__global__ __launch_bounds__(256) void embed_kernel(
    const int* __restrict__ idx, const float* __restrict__ te,
    const float* __restrict__ pe, float* __restrict__ x) {
    int row = blockIdx.x;
    int t = row & (NT - 1);
    int id = idx[row];
    const float4 a = reinterpret_cast<const float4*>(te + (size_t)id * NC)[threadIdx.x];
    const float4 b = reinterpret_cast<const float4*>(pe + (size_t)t * NC)[threadIdx.x];
    float4 o; o.x = a.x + b.x; o.y = a.y + b.y; o.z = a.z + b.z; o.w = a.w + b.w;
    reinterpret_cast<float4*>(x + (size_t)row * NC)[threadIdx.x] = o;
}

// ---------------- f32 -> bf16 bulk convert (tok_emb)
__global__ __launch_bounds__(256) void cvt_bf16_kernel(
    const float* __restrict__ in, unsigned short* __restrict__ out, size_t n4) {
    size_t i = (size_t)blockIdx.x * 256 + threadIdx.x;
    if (i >= n4) return;
    float4 v = reinterpret_cast<const float4*>(in)[i];
    uint2 u;
    u.x = (unsigned)f2bf(v.x) | ((unsigned)f2bf(v.y) << 16);
    u.y = (unsigned)f2bf(v.z) | ((unsigned)f2bf(v.w) << 16);
    reinterpret_cast<uint2*>(out)[i] = u;
}

// ---------------- fused weight transpose+convert for one layer (4 matrices)
__global__ __launch_bounds__(256) void wtrans4_kernel(
    const float* __restrict__ s0, const float* __restrict__ s1,
    const float* __restrict__ s2, const float* __restrict__ s3,
    unsigned short* __restrict__ d0, unsigned short* __restrict__ d1,
    unsigned short* __restrict__ d2, unsigned short* __restrict__ d3) {
    __shared__ float tile[32][33];
    int bid = blockIdx.x;
    const float* W; unsigned short* D; int K, N, tn, tk;
    if (bid < 3072)      { W = s0; D = d0; K = 1024; N = 3072; tn = bid % 96;  tk = bid / 96; }
    else if (bid < 4096) { int t = bid - 3072; W = s1; D = d1; K = 1024; N = 1024; tn = t & 31;  tk = t >> 5; }
    else if (bid < 8192) { int t = bid - 4096; W = s2; D = d2; K = 1024; N = 4096; tn = t & 127; tk = t >> 7; }
    else                 { int t = bid - 8192; W = s3; D = d3; K = 4096; N = 1024; tn = t & 31;  tk = t >> 5; }
    int n0 = tn * 32, k0 = tk * 32;
    int tx = threadIdx.x, ty = threadIdx.y;  // (32,8)
#pragma unroll
    for (int i = 0; i < 4; ++i)
        tile[ty + i * 8][tx] = W[(size_t)(k0 + ty + i * 8) * N + n0 + tx];
    __syncthreads();
#pragma unroll
    for (int i = 0; i < 4; ++i)
        D[(size_t)(n0 + ty + i * 8) * K + k0 + tx] = f2bf(tile[tx][ty + i * 8]);
}

// ---------------- layernorm (f32 in -> bf16 out), one block per row, C=1024
__global__ __launch_bounds__(256) void ln_kernel(
    const float* __restrict__ x, const float* __restrict__ gam,
    const float* __restrict__ bet, unsigned short* __restrict__ out) {
    __shared__ float red[4];
    int row = blockIdx.x, tid = threadIdx.x;
    const float4 v = reinterpret_cast<const float4*>(x + (size_t)row * NC)[tid];
    float s = v.x + v.y + v.z + v.w;
#pragma unroll
    for (int m = 32; m >= 1; m >>= 1) s += __shfl_xor(s, m, 64);
    if ((tid & 63) == 0) red[tid >> 6] = s;
    __syncthreads();
    float mean = (red[0] + red[1] + red[2] + red[3]) * (1.0f / NC);
    __syncthreads();
    float dx = v.x - mean, dy = v.y - mean, dz = v.z - mean, dw = v.w - mean;
    float q = dx * dx + dy * dy + dz * dz + dw * dw;
#pragma unroll
    for (int m = 32; m >= 1; m >>= 1) q += __shfl_xor(q, m, 64);
    if ((tid & 63) == 0) red[tid >> 6] = q;
    __syncthreads();
    float var = (red[0] + red[1] + red[2] + red[3]) * (1.0f / NC);
    float rstd = rsqrtf(var + 1e-5f);
    int c = tid * 4;
    const float4 g4 = reinterpret_cast<const float4*>(gam)[tid];
    const float4 b4 = reinterpret_cast<const float4*>(bet)[tid];
    uint2 u;
    u.x = (unsigned)f2bf(dx * rstd * g4.x + b4.x) |
          ((unsigned)f2bf(dy * rstd * g4.y + b4.y) << 16);
    u.y = (unsigned)f2bf(dz * rstd * g4.z + b4.z) |
          ((unsigned)f2bf(dw * rstd * g4.w + b4.w) << 16);
    reinterpret_cast<uint2*>(out + (size_t)row * NC + c)[0] = u;
}

// ---------------- GEMM: 128x128 tile, 3-buffer ring, counted vmcnt. (proj)
template<int ACT, bool BIAS, bool OUTBF16, bool ATOMIC>
__global__ __launch_bounds__(256) void gemm_kernel(
    const unsigned short* __restrict__ A, const unsigned short* __restrict__ Bt,
    const float* __restrict__ bias, void* __restrict__ Cout,
    int N, int K, int ldc, int ksub) {
    __shared__ unsigned short lds[3][2][128 * 32];
    const int tid = threadIdx.x;
    const int lane = tid & 63;
    const int wave = tid >> 6;
    const int wm = wave >> 1, wn = wave & 1;
    const int lr = lane & 15, lg = lane >> 4;
    const int m0 = blockIdx.x * 128, n0 = blockIdx.y * 128;
    const int kbeg = blockIdx.z * ksub;

    const int r0 = tid >> 2;
    const int c0 = (tid & 3) * 8;
    const unsigned short* Ag0 = A + (size_t)(m0 + r0) * K + c0;
    const unsigned short* Ag1 = A + (size_t)(m0 + r0 + 64) * K + c0;
    const unsigned short* Bg0 = Bt + (size_t)(n0 + r0) * K + c0;
    const unsigned short* Bg1 = Bt + (size_t)(n0 + r0 + 64) * K + c0;
    const int dw0 = wave * 512;
    const int dw1 = 2048 + wave * 512;

    const f32x4 zero4 = {0.0f, 0.0f, 0.0f, 0.0f};
    f32x4 acc[4][4];
#pragma unroll
    for (int i = 0; i < 4; ++i)
#pragma unroll
        for (int j = 0; j < 4; ++j) acc[i][j] = zero4;

    auto stage = [&](int buf, int k0) {
        gload16(Ag0 + k0, &lds[buf][0][dw0]);
        gload16(Ag1 + k0, &lds[buf][0][dw1]);
        gload16(Bg0 + k0, &lds[buf][1][dw0]);
        gload16(Bg1 + k0, &lds[buf][1][dw1]);
    };

    const int nt = ksub >> 5;
    stage(0, kbeg);
    stage(1, kbeg + 32);
    vwait<4>();
    barrier_mem();
    int b0 = 0, b1 = 1, b2 = 2;
    for (int t = 0; t < nt; ++t) {
        const bool pf = (t + 2 < nt);
        if (pf) stage(b2, kbeg + (t + 2) * 32);
        bf16x8 af[4], bfr[4];
#pragma unroll
        for (int f = 0; f < 4; ++f) {
            af[f]  = *reinterpret_cast<const bf16x8*>(&lds[b0][0][(wm * 64 + f * 16 + lr) * 32 + lg * 8]);
            bfr[f] = *reinterpret_cast<const bf16x8*>(&lds[b0][1][(wn * 64 + f * 16 + lr) * 32 + lg * 8]);
        }
#pragma unroll
        for (int i = 0; i < 4; ++i)
#pragma unroll
            for (int j = 0; j < 4; ++j)
                acc[i][j] = __builtin_amdgcn_mfma_f32_16x16x32_bf16(af[i], bfr[j], acc[i][j], 0, 0, 0);
        if (t + 1 < nt) {
            if (pf) vwait<4>(); else vwait<0>();
            barrier_mem();
        }
        int tmp = b0; b0 = b1; b1 = b2; b2 = tmp;
    }

#pragma unroll
    for (int i = 0; i < 4; ++i) {
#pragma unroll
        for (int j = 0; j < 4; ++j) {
            int col = n0 + wn * 64 + j * 16 + lr;
            float bv = (BIAS && kbeg == 0) ? bias[col] : 0.0f;
#pragma unroll
            for (int r = 0; r < 4; ++r) {
                int row = m0 + wm * 64 + i * 16 + lg * 4 + r;
                float v = acc[i][j][r] + bv;
                if (ACT == 1) v = 0.5f * v * (1.0f + erff(v * 0.70710678118654752f));
                if (ATOMIC) {
                    atomicAdd(reinterpret_cast<float*>(Cout) + (size_t)row * ldc + col, v);
                } else if (OUTBF16) {
                    reinterpret_cast<unsigned short*>(Cout)[(size_t)row * ldc + col] = f2bf(v);
                } else {
                    reinterpret_cast<float*>(Cout)[(size_t)row * ldc + col] = v;
                }
            }
        }
    }
}

// ---------------- 256-wide GEMM (128x256, 3-slot ring) — qkv/ffn1/ffn2/head
template<int ACT, bool BIAS, bool OUTBF16, bool NEDGE, bool ATOMIC>
__global__ __launch_bounds__(512, 4) void gemm256_kernel(
    const unsigned short* __restrict__ A, const unsigned short* __restrict__ Bt,
    const float* __restrict__ bias, void* __restrict__ Cout,
    int N, int K, int ldc, int ksub) {
    __shared__ unsigned short lds[3][12288];
    const int tid = threadIdx.x;
    const int lane = tid & 63, wid = tid >> 6;
    const int wm = wid >> 2, wn = wid & 3;
    const int lr = lane & 15, lg = lane >> 4;

    const int qx = gridDim.x >> 3;
    const int orig = blockIdx.x;
    const int wg = (orig & 7) * qx + (orig >> 3);
    const int m0 = (wg & 15) * 128;
    const int n0 = (wg >> 4) * 256;
    const int kbeg2 = blockIdx.y * ksub * 2;

    int rA, kA;
    { int pr = tid >> 3, s = tid & 7; int li = s ^ (pr & 7);
      rA = 2 * pr + (li >> 2); kA = (li & 3) << 4; }
    int rB1, kB1;
    { int o = tid + 512; int pr = o >> 3, s = o & 7; int li = s ^ (pr & 7);
      rB1 = 2 * pr + (li >> 2); kB1 = (li & 3) << 4; }
    int nrow0 = n0 + rA, nrow1 = n0 + rB1;
    if (NEDGE) { nrow0 = min(nrow0, N - 1); nrow1 = min(nrow1, N - 1); }
    const char* pAg  = (const char*)A  + (size_t)(m0 + rA) * (2 * K) + kA + kbeg2;
    const char* pBg0 = (const char*)Bt + (size_t)nrow0 * (2 * K) + kA + kbeg2;
    const char* pBg1 = (const char*)Bt + (size_t)nrow1 * (2 * K) + kB1 + kbeg2;
    const int dst = wid * 512;

    const int swz = (((lr & 1) << 6) | (lg << 4)) ^ (((lr >> 1) & 7) << 4);
    const int pbA = (wm * 32 + (lr >> 1)) * 128 + swz;
    const int pbB = (wn * 32 + (lr >> 1)) * 128 + swz;

    const f32x4 zero4 = {0.0f, 0.0f, 0.0f, 0.0f};
    f32x4 acc[4][4];
#pragma unroll
    for (int i = 0; i < 4; ++i)
#pragma unroll
        for (int j = 0; j < 4; ++j) acc[i][j] = zero4;

    auto stage3 = [&](int slot, int koff) {
        unsigned short* base = &lds[slot][0];
        gload16((const unsigned short*)(pAg  + koff), base + dst);
        gload16((const unsigned short*)(pBg0 + koff), base + 4096 + dst);
        gload16((const unsigned short*)(pBg1 + koff), base + 8192 + dst);
    };
    auto rdA = [&](int slot, int mf) -> bf16x8 {
        return *reinterpret_cast<const bf16x8*>(
            (const char*)&lds[slot][0] + pbA + mf * 1024);
    };
    auto rdB = [&](int slot, int nf) -> bf16x8 {
        return *reinterpret_cast<const bf16x8*>(
            (const char*)&lds[slot][0] + 8192 + pbB + nf * 1024);
    };

    const int nt = ksub >> 5;
    stage3(0, 0);
    stage3(1, 64);
    vwait<3>();
    barrier_mem();
    int b0 = 0, b1 = 1, b2 = 2;
    for (int t = 0; t < nt; ++t) {
        const bool pf = (t + 2 < nt);
        if (pf) stage3(b2, (t + 2) * 64);
        bf16x8 bf0 = rdB(b0, 0), bf1 = rdB(b0, 1), bf2 = rdB(b0, 2), bf3 = rdB(b0, 3);
        bf16x8 a0 = rdA(b0, 0), a1 = rdA(b0, 1), a2 = rdA(b0, 2), a3 = rdA(b0, 3);
        __builtin_amdgcn_s_setprio(1);
        acc[0][0] = __builtin_amdgcn_mfma_f32_16x16x32_bf16(a0, bf0, acc[0][0], 0, 0, 0);
        acc[0][1] = __builtin_amdgcn_mfma_f32_16x16x32_bf16(a0, bf1, acc[0][1], 0, 0, 0);
        acc[0][2] = __builtin_amdgcn_mfma_f32_16x16x32_bf16(a0, bf2, acc[0][2], 0, 0, 0);
        acc[0][3] = __builtin_amdgcn_mfma_f32_16x16x32_bf16(a0, bf3, acc[0][3], 0, 0, 0);
        acc[1][0] = __builtin_amdgcn_mfma_f32_16x16x32_bf16(a1, bf0, acc[1][0], 0, 0, 0);
        acc[1][1] = __builtin_amdgcn_mfma_f32_16x16x32_bf16(a1, bf1, acc[1][1], 0, 0, 0);
        acc[1][2] = __builtin_amdgcn_mfma_f32_16x16x32_bf16(a1, bf2, acc[1][2], 0, 0, 0);
        acc[1][3] = __builtin_amdgcn_mfma_f32_16x16x32_bf16(a1, bf3, acc[1][3], 0, 0, 0);
        acc[2][0] = __builtin_amdgcn_mfma_f32_16x16x32_bf16(a2, bf0, acc[2][0], 0, 0, 0);
        acc[2][1] = __builtin_amdgcn_mfma_f32_16x16x32_bf16(a2, bf1, acc[2][1], 0, 0, 0);
        acc[2][2] = __builtin_amdgcn_mfma_f32_16x16x32_bf16(a2, bf2, acc[2][2], 0, 0, 0);
        acc[2][3] = __builtin_amdgcn_mfma_f32_16x16x32_bf16(a2, bf3, acc[2][3], 0, 0, 0);
        acc[3][0] = __builtin_amdgcn_mfma_f32_16x16x32_bf16(a3, bf0, acc[3][0], 0, 0, 0);
        acc[3][1] = __builtin_amdgcn_mfma_f32_16x16x32_bf16(a3, bf1, acc[3][1], 0, 0, 0);
        acc[3][2] = __builtin_amdgcn_mfma_f32_16x16x32_bf16(a3, bf2, acc[3][2], 0, 0, 0);
        acc[3][3] = __builtin_amdgcn_mfma_f32_16x16x32_bf16(a3, bf3, acc[3][3], 0, 0, 0);
        __builtin_amdgcn_s_setprio(0);
        if (t + 1 < nt) {
            if (pf) vwait<3>(); else vwait<0>();
            barrier_mem();
        }
        int tmp = b0; b0 = b1; b1 = b2; b2 = tmp;
    }

#pragma unroll
    for (int mf = 0; mf < 4; ++mf)
#pragma unroll
        for (int nf = 0; nf < 4; ++nf) {
            int col = n0 + wn * 64 + nf * 16 + lr;
            if (NEDGE && col >= N) continue;
            float bv = (BIAS && blockIdx.y == 0) ? bias[col] : 0.0f;
#pragma unroll
            for (int r = 0; r < 4; ++r) {
                int row = m0 + wm * 64 + mf * 16 + lg * 4 + r;
                float v = acc[mf][nf][r] + bv;
                if (ACT == 1) v = 0.5f * v * (1.0f + erff(v * 0.70710678118654752f));
                if (ATOMIC)
                    atomicAdd(reinterpret_cast<float*>(Cout) + (size_t)row * ldc + col, v);
                else if (OUTBF16)
                    reinterpret_cast<unsigned short*>(Cout)[(size_t)row * ldc + col] = f2bf(v);
                else
                    reinterpret_cast<float*>(Cout)[(size_t)row * ldc + col] = v;
            }
        }
}

// ---------------- V transpose: qkv v-part [t][d] -> vt[b][h][d][t] (bf16)
__global__ __launch_bounds__(256) void vtrans_kernel(
    const unsigned short* __restrict__ qkv, unsigned short* __restrict__ vt) {
    __shared__ unsigned short tile[32][33];
    int bh = blockIdx.z; int b = bh >> 4, h = bh & 15;
    int t0 = blockIdx.x * 32, d0 = blockIdx.y * 32;
    int tx = threadIdx.x, ty = threadIdx.y;  // (32,8)
#pragma unroll
    for (int i = 0; i < 4; ++i)
        tile[ty + i * 8][tx] =
            qkv[(size_t)(b * NT + t0 + ty + i * 8) * 3072 + 2048 + h * 64 + d0 + tx];
    __syncthreads();
#pragma unroll
    for (int i = 0; i < 4; ++i)
        vt[((size_t)(b * NH + h) * 64 + d0 + ty + i * 8) * NT + t0 + tx] = tile[tx][ty + i * 8];
}

// ---------------- causal flash attention, split-K over key tiles (2 splits).
// Writes UNNORMALIZED O-accum (bf16 partials) + per-row (m, l) in f32.
__global__ __launch_bounds__(64) void attn_kernel(
    const unsigned short* __restrict__ qkv, const unsigned short* __restrict__ vt,
    unsigned short* __restrict__ opart, float2* __restrict__ ml) {
    __shared__ unsigned short Vs[64][72];
    __shared__ unsigned short Ps[32][72];
    const int qt = blockIdx.x;
    const int h  = blockIdx.y;
    const int b  = blockIdx.z >> 1;
    const int sp = blockIdx.z & 1;
    const int lane = threadIdx.x;
    const int lr = lane & 15, lg = lane >> 4;

    const unsigned short* qbase = qkv + (size_t)(b * NT + qt * 32) * 3072 + h * 64;
    bf16x8 qf[2][2];
#pragma unroll
    for (int mf = 0; mf < 2; ++mf)
#pragma unroll
        for (int kc = 0; kc < 2; ++kc)
            qf[mf][kc] = *reinterpret_cast<const bf16x8*>(
                qbase + (size_t)(mf * 16 + lr) * 3072 + kc * 32 + lg * 8);

    const f32x4 zero4 = {0.0f, 0.0f, 0.0f, 0.0f};
    f32x4 oacc[2][4];
    float mrow[2][4], lsum[2][4];
#pragma unroll
    for (int mf = 0; mf < 2; ++mf) {
#pragma unroll
        for (int nf = 0; nf < 4; ++nf) oacc[mf][nf] = zero4;
#pragma unroll
        for (int r = 0; r < 4; ++r) { mrow[mf][r] = -INFINITY; lsum[mf][r] = 0.0f; }
    }

    const int qend = qt * 32 + 32;
    const int nkt = (qend + 63) >> 6;
    const int khalf = (nkt + 1) >> 1;
    const int kt0 = sp ? khalf : 0;
    const int kt1 = sp ? nkt : khalf;
    const unsigned short* kbase = qkv + (size_t)(b * NT) * 3072 + NC + h * 64;
    const unsigned short* vbase = vt + (size_t)((b * NH + h) * 64) * NT;

    for (int kt = kt0; kt < kt1; ++kt) {
        __syncthreads();
#pragma unroll
        for (int i = 0; i < 8; ++i) {
            int chunk = lane + i * 64;
            int d = chunk >> 3;
            int kk = (chunk & 7) * 8;
            *reinterpret_cast<bf16x8*>(&Vs[d][kk]) =
                *reinterpret_cast<const bf16x8*>(vbase + (size_t)d * NT + kt * 64 + kk);
        }
        f32x4 s[2][4];
#pragma unroll
        for (int mf = 0; mf < 2; ++mf)
#pragma unroll
            for (int jf = 0; jf < 4; ++jf) s[mf][jf] = zero4;
#pragma unroll
        for (int kc = 0; kc < 2; ++kc) {
            bf16x8 kf[4];
#pragma unroll
            for (int jf = 0; jf < 4; ++jf)
                kf[jf] = *reinterpret_cast<const bf16x8*>(
                    kbase + (size_t)(kt * 64 + jf * 16 + lr) * 3072 + kc * 32 + lg * 8);
#pragma unroll
            for (int mf = 0; mf < 2; ++mf)
#pragma unroll
                for (int jf = 0; jf < 4; ++jf)
                    s[mf][jf] = __builtin_amdgcn_mfma_f32_16x16x32_bf16(
                        qf[mf][kc], kf[jf], s[mf][jf], 0, 0, 0);
        }
        const bool lastt = (kt == nkt - 1);
#pragma unroll
        for (int mf = 0; mf < 2; ++mf) {
#pragma unroll
            for (int r = 0; r < 4; ++r) {
                int rowg = qt * 32 + mf * 16 + lg * 4 + r;
                float tmax = -INFINITY;
#pragma unroll
                for (int jf = 0; jf < 4; ++jf) {
                    float v = s[mf][jf][r] * 0.125f;
                    if (lastt) {
                        int colg = kt * 64 + jf * 16 + lr;
                        if (colg > rowg) v = -INFINITY;
                    }
                    s[mf][jf][r] = v;
                    tmax = fmaxf(tmax, v);
                }
                tmax = fmaxf(tmax, __shfl_xor(tmax, 1, 64));
                tmax = fmaxf(tmax, __shfl_xor(tmax, 2, 64));
                tmax = fmaxf(tmax, __shfl_xor(tmax, 4, 64));
                tmax = fmaxf(tmax, __shfl_xor(tmax, 8, 64));
                float mnew = fmaxf(mrow[mf][r], tmax);
                float corr = __expf(mrow[mf][r] - mnew);
                float ps = 0.0f;
#pragma unroll
                for (int jf = 0; jf < 4; ++jf) {
                    float p = __expf(s[mf][jf][r] - mnew);
                    s[mf][jf][r] = p;
                    ps += p;
                }
                ps += __shfl_xor(ps, 1, 64);
                ps += __shfl_xor(ps, 2, 64);
                ps += __shfl_xor(ps, 4, 64);
                ps += __shfl_xor(ps, 8, 64);
                lsum[mf][r] = lsum[mf][r] * corr + ps;
                mrow[mf][r] = mnew;
#pragma unroll
                for (int nf = 0; nf < 4; ++nf) oacc[mf][nf][r] *= corr;
            }
        }
#pragma unroll
        for (int mf = 0; mf < 2; ++mf)
#pragma unroll
            for (int jf = 0; jf < 4; ++jf)
#pragma unroll
                for (int r = 0; r < 4; ++r)
                    Ps[mf * 16 + lg * 4 + r][jf * 16 + lr] = f2bf(s[mf][jf][r]);
        __syncthreads();
#pragma unroll
        for (int kc = 0; kc < 2; ++kc) {
            bf16x8 pf[2], vf[4];
#pragma unroll
            for (int mf = 0; mf < 2; ++mf)
                pf[mf] = *reinterpret_cast<const bf16x8*>(&Ps[mf * 16 + lr][kc * 32 + lg * 8]);
#pragma unroll
            for (int nf = 0; nf < 4; ++nf)
                vf[nf] = *reinterpret_cast<const bf16x8*>(&Vs[nf * 16 + lr][kc * 32 + lg * 8]);
#pragma unroll
            for (int mf = 0; mf < 2; ++mf)
#pragma unroll
                for (int nf = 0; nf < 4; ++nf)
                    oacc[mf][nf] = __builtin_amdgcn_mfma_f32_16x16x32_bf16(
                        pf[mf], vf[nf], oacc[mf][nf], 0, 0, 0);
        }
    }

    const size_t rowbase = (size_t)sp * 2048 + b * NT + qt * 32;
    unsigned short* op = opart + rowbase * NC + h * 64;
#pragma unroll
    for (int mf = 0; mf < 2; ++mf)
#pragma unroll
        for (int nf = 0; nf < 4; ++nf)
#pragma unroll
            for (int r = 0; r < 4; ++r)
                op[(size_t)(mf * 16 + lg * 4 + r) * NC + nf * 16 + lr] = f2bf(oacc[mf][nf][r]);
    if (lr == 0) {
#pragma unroll
        for (int mf = 0; mf < 2; ++mf)
#pragma unroll
            for (int r = 0; r < 4; ++r)
                ml[(rowbase + mf * 16 + lg * 4 + r) * NH + h] =
                    make_float2(mrow[mf][r], lsum[mf][r]);
    }
}

// ---------------- combine 2 attention splits (bf16 partials) -> bf16 O
__global__ __launch_bounds__(256) void attn_combine_kernel(
    const unsigned short* __restrict__ opart, const float2* __restrict__ ml,
    unsigned short* __restrict__ o) {
    const int row = blockIdx.x;
    const int tid = threadIdx.x;
    const int h = tid >> 4;
    float2 a = ml[(size_t)row * NH + h];
    float2 c = ml[(size_t)(2048 + row) * NH + h];
    float m = fmaxf(a.x, c.x);
    float w0 = __expf(a.x - m), w1 = __expf(c.x - m);
    float inv = 1.0f / (a.y * w0 + c.y * w1);
    uint2 u0 = reinterpret_cast<const uint2*>(opart + (size_t)row * NC)[tid];
    uint2 u1 = reinterpret_cast<const uint2*>(opart + (size_t)(2048 + row) * NC)[tid];
    float o0x = bf2f((unsigned short)(u0.x & 0xFFFF)), o0y = bf2f((unsigned short)(u0.x >> 16));
    float o0z = bf2f((unsigned short)(u0.y & 0xFFFF)), o0w = bf2f((unsigned short)(u0.y >> 16));
    float o1x = bf2f((unsigned short)(u1.x & 0xFFFF)), o1y = bf2f((unsigned short)(u1.x >> 16));
    float o1z = bf2f((unsigned short)(u1.y & 0xFFFF)), o1w = bf2f((unsigned short)(u1.y >> 16));
    uint2 u;
    u.x = (unsigned)f2bf((o0x * w0 + o1x * w1) * inv) |
          ((unsigned)f2bf((o0y * w0 + o1y * w1) * inv) << 16);
    u.y = (unsigned)f2bf((o0z * w0 + o1z * w1) * inv) |
          ((unsigned)f2bf((o0w * w0 + o1w * w1) * inv) << 16);
    reinterpret_cast<uint2*>(o + (size_t)row * NC)[tid] = u;
}

extern "C" void kernel_launch(void* const* d_in, const int* in_sizes, int n_in,
                              void* d_out, int out_size, void* d_ws, size_t ws_size,
                              hipStream_t stream) {
    (void)in_sizes; (void)n_in; (void)out_size; (void)ws_size;
    const int*   idx    = (const int*)  d_in[0];
    const float* tok    = (const float*)d_in[1];
    const float* pos    = (const float*)d_in[2];
    const float* qkv_w  = (const float*)d_in[3];
    const float* qkv_b  = (const float*)d_in[4];
    const float* out_w  = (const float*)d_in[5];
    const float* out_b  = (const float*)d_in[6];
    const float* ln1_s  = (const float*)d_in[7];
    const float* ln1_b  = (const float*)d_in[8];
    const float* ln2_s  = (const float*)d_in[9];
    const float* ln2_b  = (const float*)d_in[10];
    const float* ffn_w1 = (const float*)d_in[11];
    const float* ffn_b1 = (const float*)d_in[12];
    const float* ffn_w2 = (const float*)d_in[13];
    const float* ffn_b2 = (const float*)d_in[14];
    const float* lnf_s  = (const float*)d_in[15];
    const float* lnf_b  = (const float*)d_in[16];

    char* p = (char*)d_ws;
    float* x              = (float*)p;          p += (size_t)NM * NC * 4;
    unsigned short* hbuf  = (unsigned short*)p; p += (size_t)NM * NC * 2;
    unsigned short* qkvb  = (unsigned short*)p; p += (size_t)NM * 3 * NC * 2;
    unsigned short* obuf  = (unsigned short*)p; p += (size_t)NM * NC * 2;
    unsigned short* gbuf  = (unsigned short*)p; p += (size_t)NM * NFF * 2;
    unsigned short* vtb   = (unsigned short*)p; p += (size_t)NB * NH * 64 * NT * 2;
    unsigned short* wq    = (unsigned short*)p; p += (size_t)3 * NC * NC * 2;
    unsigned short* wo    = (unsigned short*)p; p += (size_t)NC * NC * 2;
    unsigned short* w1    = (unsigned short*)p; p += (size_t)NC * NFF * 2;
    unsigned short* w2    = (unsigned short*)p; p += (size_t)NFF * NC * 2;
    unsigned short* temb  = (unsigned short*)p; p += (size_t)NV * NC * 2;
    unsigned short* opart = (unsigned short*)p; p += (size_t)2 * NM * NC * 2;
    float2* mlbuf         = (float2*)p;         p += (size_t)2 * NM * NH * 8;

    {
        size_t n4 = (size_t)NV * NC / 4;
        int blocks = (int)((n4 + 255) / 256);
        cvt_bf16_kernel<<<blocks, 256, 0, stream>>>(tok, temb, n4);
    }
    embed_kernel<<<NM, 256, 0, stream>>>(idx, tok, pos, x);

    for (int l = 0; l < NL; ++l) {
        wtrans4_kernel<<<12288, dim3(32, 8), 0, stream>>>(
            qkv_w + (size_t)l * NC * 3 * NC, out_w + (size_t)l * NC * NC,
            ffn_w1 + (size_t)l * NC * NFF, ffn_w2 + (size_t)l * NFF * NC,
            wq, wo, w1, w2);

        ln_kernel<<<NM, 256, 0, stream>>>(x, ln1_s + (size_t)l * NC, ln1_b + (size_t)l * NC, hbuf);
        gemm256_kernel<0, true, true, false, false><<<dim3(192), 512, 0, stream>>>(
            hbuf, wq, qkv_b + (size_t)l * 3 * NC, qkvb, 3 * NC, NC, 3 * NC, NC);
        vtrans_kernel<<<dim3(32, 2, 32), dim3(32, 8), 0, stream>>>(qkvb, vtb);
        attn_kernel<<<dim3(32, 16, 4), 64, 0, stream>>>(qkvb, vtb, opart, mlbuf);
        attn_combine_kernel<<<NM, 256, 0, stream>>>(opart, mlbuf, obuf);
        gemm_kernel<0, true, false, true><<<dim3(16, 8, 2), 256, 0, stream>>>(
            obuf, wo, out_b + (size_t)l * NC, x, NC, NC, NC, NC / 2);
        ln_kernel<<<NM, 256, 0, stream>>>(x, ln2_s + (size_t)l * NC, ln2_b + (size_t)l * NC, hbuf);
        gemm256_kernel<1, true, true, false, false><<<dim3(256), 512, 0, stream>>>(
            hbuf, w1, ffn_b1 + (size_t)l * NFF, gbuf, NFF, NC, NFF, NC);
        gemm256_kernel<0, true, false, false, true><<<dim3(64, 4), 512, 0, stream>>>(
            gbuf, w2, ffn_b2 + (size_t)l * NC, x, NC, NFF, NC, NFF / 4);
    }
    ln_kernel<<<NM, 256, 0, stream>>>(x, lnf_s, lnf_b, hbuf);
    // tied head: 128x256 tiles, grid = 16 M x 197 N = 3152 (%8==0)
    gemm256_kernel<0, false, false, true, false><<<dim3(16 * 197), 512, 0, stream>>>(
        hbuf, temb, nullptr, d_out, NV, NC, NV, NC);
}

// Round 15
// 1830.777 us; speedup vs baseline: 1.0639x; 1.0005x over previous
//
#include <hip/hip_runtime.h>
#include <hip/hip_bf16.h>

#define NL 8
#define NV 50257
#define NC 1024
#define NH 16
#define NT 1024
#define NFF 4096
#define NB 2
#define NM (NB*NT)   // 2048 rows

typedef __attribute__((ext_vector_type(8))) short bf16x8;
typedef __attribute__((ext_vector_type(4))) float f32x4;

__device__ __forceinline__ unsigned short f2bf(float f) {
    union { float f; unsigned u; } a; a.f = f;
    unsigned r = a.u + 0x7FFFu + ((a.u >> 16) & 1u);
    return (unsigned short)(r >> 16);
}
__device__ __forceinline__ float bf2f(unsigned short s) {
    union { unsigned u; float f; } a; a.u = (unsigned)s << 16;
    return a.f;
}

__device__ __forceinline__ void gload16(const unsigned short* g, unsigned short* l) {
    __builtin_amdgcn_global_load_lds(
        (const __attribute__((address_space(1))) unsigned int*)g,
        (__attribute__((address_space(3))) unsigned int*)l,
        16, 0, 0);
}

template<int VN> __device__ __forceinline__ void vwait() {
    asm volatile("s_waitcnt vmcnt(%0)" :: "n"(VN) : "memory");
}
__device__ __forceinline__ void barrier_mem() {
    asm volatile("" ::: "memory");
    __builtin_amdgcn_s_barrier();
    asm volatile("" ::: "memory");
}

// ---------------- embedding: x[b,t,:] = tok_emb[idx[b,t],:] + pos_emb[t,:]
__global__ __launch_bounds__(256) void embed_kernel(
    const int* __restrict__ idx, const float* __restrict__ te,
    const float* __restrict__ pe, float* __restrict__ x) {
    int row = blockIdx.x;
    int t = row & (NT - 1);
    int id = idx[row];
    const float4 a = reinterpret_cast<const float4*>(te + (size_t)id * NC)[threadIdx.x];
    const float4 b = reinterpret_cast<const float4*>(pe + (size_t)t * NC)[threadIdx.x];
    float4 o; o.x = a.x + b.x; o.y = a.y + b.y; o.z = a.z + b.z; o.w = a.w + b.w;
    reinterpret_cast<float4*>(x + (size_t)row * NC)[threadIdx.x] = o;
}

// ---------------- f32 -> bf16 bulk convert (tok_emb)
__global__ __launch_bounds__(256) void cvt_bf16_kernel(
    const float* __restrict__ in, unsigned short* __restrict__ out, size_t n4) {
    size_t i = (size_t)blockIdx.x * 256 + threadIdx.x;
    if (i >= n4) return;
    float4 v = reinterpret_cast<const float4*>(in)[i];
    uint2 u;
    u.x = (unsigned)f2bf(v.x) | ((unsigned)f2bf(v.y) << 16);
    u.y = (unsigned)f2bf(v.z) | ((unsigned)f2bf(v.w) << 16);
    reinterpret_cast<uint2*>(out)[i] = u;
}

// ---------------- fused weight transpose+convert for one layer (4 matrices)
__global__ __launch_bounds__(256) void wtrans4_kernel(
    const float* __restrict__ s0, const float* __restrict__ s1,
    const float* __restrict__ s2, const float* __restrict__ s3,
    unsigned short* __restrict__ d0, unsigned short* __restrict__ d1,
    unsigned short* __restrict__ d2, unsigned short* __restrict__ d3) {
    __shared__ float tile[32][33];
    int bid = blockIdx.x;
    const float* W; unsigned short* D; int K, N, tn, tk;
    if (bid < 3072)      { W = s0; D = d0; K = 1024; N = 3072; tn = bid % 96;  tk = bid / 96; }
    else if (bid < 4096) { int t = bid - 3072; W = s1; D = d1; K = 1024; N = 1024; tn = t & 31;  tk = t >> 5; }
    else if (bid < 8192) { int t = bid - 4096; W = s2; D = d2; K = 1024; N = 4096; tn = t & 127; tk = t >> 7; }
    else                 { int t = bid - 8192; W = s3; D = d3; K = 4096; N = 1024; tn = t & 31;  tk = t >> 5; }
    int n0 = tn * 32, k0 = tk * 32;
    int tx = threadIdx.x, ty = threadIdx.y;  // (32,8)
#pragma unroll
    for (int i = 0; i < 4; ++i)
        tile[ty + i * 8][tx] = W[(size_t)(k0 + ty + i * 8) * N + n0 + tx];
    __syncthreads();
#pragma unroll
    for (int i = 0; i < 4; ++i)
        D[(size_t)(n0 + ty + i * 8) * K + k0 + tx] = f2bf(tile[tx][ty + i * 8]);
}

// ---------------- layernorm (f32 in -> bf16 out), one block per row, C=1024
__global__ __launch_bounds__(256) void ln_kernel(
    const float* __restrict__ x, const float* __restrict__ gam,
    const float* __restrict__ bet, unsigned short* __restrict__ out) {
    __shared__ float red[4];
    int row = blockIdx.x, tid = threadIdx.x;
    const float4 v = reinterpret_cast<const float4*>(x + (size_t)row * NC)[tid];
    float s = v.x + v.y + v.z + v.w;
#pragma unroll
    for (int m = 32; m >= 1; m >>= 1) s += __shfl_xor(s, m, 64);
    if ((tid & 63) == 0) red[tid >> 6] = s;
    __syncthreads();
    float mean = (red[0] + red[1] + red[2] + red[3]) * (1.0f / NC);
    __syncthreads();
    float dx = v.x - mean, dy = v.y - mean, dz = v.z - mean, dw = v.w - mean;
    float q = dx * dx + dy * dy + dz * dz + dw * dw;
#pragma unroll
    for (int m = 32; m >= 1; m >>= 1) q += __shfl_xor(q, m, 64);
    if ((tid & 63) == 0) red[tid >> 6] = q;
    __syncthreads();
    float var = (red[0] + red[1] + red[2] + red[3]) * (1.0f / NC);
    float rstd = rsqrtf(var + 1e-5f);
    int c = tid * 4;
    const float4 g4 = reinterpret_cast<const float4*>(gam)[tid];
    const float4 b4 = reinterpret_cast<const float4*>(bet)[tid];
    uint2 u;
    u.x = (unsigned)f2bf(dx * rstd * g4.x + b4.x) |
          ((unsigned)f2bf(dy * rstd * g4.y + b4.y) << 16);
    u.y = (unsigned)f2bf(dz * rstd * g4.z + b4.z) |
          ((unsigned)f2bf(dw * rstd * g4.w + b4.w) << 16);
    reinterpret_cast<uint2*>(out + (size_t)row * NC + c)[0] = u;
}

// ---------------- GEMM: 128x128 tile, 3-buffer ring, counted vmcnt. (proj)
template<int ACT, bool BIAS, bool OUTBF16, bool ATOMIC>
__global__ __launch_bounds__(256) void gemm_kernel(
    const unsigned short* __restrict__ A, const unsigned short* __restrict__ Bt,
    const float* __restrict__ bias, void* __restrict__ Cout,
    int N, int K, int ldc, int ksub) {
    __shared__ unsigned short lds[3][2][128 * 32];
    const int tid = threadIdx.x;
    const int lane = tid & 63;
    const int wave = tid >> 6;
    const int wm = wave >> 1, wn = wave & 1;
    const int lr = lane & 15, lg = lane >> 4;
    const int m0 = blockIdx.x * 128, n0 = blockIdx.y * 128;
    const int kbeg = blockIdx.z * ksub;

    const int r0 = tid >> 2;
    const int c0 = (tid & 3) * 8;
    const unsigned short* Ag0 = A + (size_t)(m0 + r0) * K + c0;
    const unsigned short* Ag1 = A + (size_t)(m0 + r0 + 64) * K + c0;
    const unsigned short* Bg0 = Bt + (size_t)(n0 + r0) * K + c0;
    const unsigned short* Bg1 = Bt + (size_t)(n0 + r0 + 64) * K + c0;
    const int dw0 = wave * 512;
    const int dw1 = 2048 + wave * 512;

    const f32x4 zero4 = {0.0f, 0.0f, 0.0f, 0.0f};
    f32x4 acc[4][4];
#pragma unroll
    for (int i = 0; i < 4; ++i)
#pragma unroll
        for (int j = 0; j < 4; ++j) acc[i][j] = zero4;

    auto stage = [&](int buf, int k0) {
        gload16(Ag0 + k0, &lds[buf][0][dw0]);
        gload16(Ag1 + k0, &lds[buf][0][dw1]);
        gload16(Bg0 + k0, &lds[buf][1][dw0]);
        gload16(Bg1 + k0, &lds[buf][1][dw1]);
    };

    const int nt = ksub >> 5;
    stage(0, kbeg);
    stage(1, kbeg + 32);
    vwait<4>();
    barrier_mem();
    int b0 = 0, b1 = 1, b2 = 2;
    for (int t = 0; t < nt; ++t) {
        const bool pf = (t + 2 < nt);
        if (pf) stage(b2, kbeg + (t + 2) * 32);
        bf16x8 af[4], bfr[4];
#pragma unroll
        for (int f = 0; f < 4; ++f) {
            af[f]  = *reinterpret_cast<const bf16x8*>(&lds[b0][0][(wm * 64 + f * 16 + lr) * 32 + lg * 8]);
            bfr[f] = *reinterpret_cast<const bf16x8*>(&lds[b0][1][(wn * 64 + f * 16 + lr) * 32 + lg * 8]);
        }
#pragma unroll
        for (int i = 0; i < 4; ++i)
#pragma unroll
            for (int j = 0; j < 4; ++j)
                acc[i][j] = __builtin_amdgcn_mfma_f32_16x16x32_bf16(af[i], bfr[j], acc[i][j], 0, 0, 0);
        if (t + 1 < nt) {
            if (pf) vwait<4>(); else vwait<0>();
            barrier_mem();
        }
        int tmp = b0; b0 = b1; b1 = b2; b2 = tmp;
    }

#pragma unroll
    for (int i = 0; i < 4; ++i) {
#pragma unroll
        for (int j = 0; j < 4; ++j) {
            int col = n0 + wn * 64 + j * 16 + lr;
            float bv = (BIAS && kbeg == 0) ? bias[col] : 0.0f;
#pragma unroll
            for (int r = 0; r < 4; ++r) {
                int row = m0 + wm * 64 + i * 16 + lg * 4 + r;
                float v = acc[i][j][r] + bv;
                if (ACT == 1) v = 0.5f * v * (1.0f + erff(v * 0.70710678118654752f));
                if (ATOMIC) {
                    atomicAdd(reinterpret_cast<float*>(Cout) + (size_t)row * ldc + col, v);
                } else if (OUTBF16) {
                    reinterpret_cast<unsigned short*>(Cout)[(size_t)row * ldc + col] = f2bf(v);
                } else {
                    reinterpret_cast<float*>(Cout)[(size_t)row * ldc + col] = v;
                }
            }
        }
    }
}

// ---------------- 256-wide GEMM (128x256, 3-slot ring) — qkv/ffn1/ffn2/head
template<int ACT, bool BIAS, bool OUTBF16, bool NEDGE, bool ATOMIC>
__global__ __launch_bounds__(512, 4) void gemm256_kernel(
    const unsigned short* __restrict__ A, const unsigned short* __restrict__ Bt,
    const float* __restrict__ bias, void* __restrict__ Cout,
    int N, int K, int ldc, int ksub) {
    __shared__ unsigned short lds[3][12288];
    const int tid = threadIdx.x;
    const int lane = tid & 63, wid = tid >> 6;
    const int wm = wid >> 2, wn = wid & 3;
    const int lr = lane & 15, lg = lane >> 4;

    const int qx = gridDim.x >> 3;
    const int orig = blockIdx.x;
    const int wg = (orig & 7) * qx + (orig >> 3);
    const int m0 = (wg & 15) * 128;
    const int n0 = (wg >> 4) * 256;
    const int kbeg2 = blockIdx.y * ksub * 2;

    int rA, kA;
    { int pr = tid >> 3, s = tid & 7; int li = s ^ (pr & 7);
      rA = 2 * pr + (li >> 2); kA = (li & 3) << 4; }
    int rB1, kB1;
    { int o = tid + 512; int pr = o >> 3, s = o & 7; int li = s ^ (pr & 7);
      rB1 = 2 * pr + (li >> 2); kB1 = (li & 3) << 4; }
    int nrow0 = n0 + rA, nrow1 = n0 + rB1;
    if (NEDGE) { nrow0 = min(nrow0, N - 1); nrow1 = min(nrow1, N - 1); }
    const char* pAg  = (const char*)A  + (size_t)(m0 + rA) * (2 * K) + kA + kbeg2;
    const char* pBg0 = (const char*)Bt + (size_t)nrow0 * (2 * K) + kA + kbeg2;
    const char* pBg1 = (const char*)Bt + (size_t)nrow1 * (2 * K) + kB1 + kbeg2;
    const int dst = wid * 512;

    const int swz = (((lr & 1) << 6) | (lg << 4)) ^ (((lr >> 1) & 7) << 4);
    const int pbA = (wm * 32 + (lr >> 1)) * 128 + swz;
    const int pbB = (wn * 32 + (lr >> 1)) * 128 + swz;

    const f32x4 zero4 = {0.0f, 0.0f, 0.0f, 0.0f};
    f32x4 acc[4][4];
#pragma unroll
    for (int i = 0; i < 4; ++i)
#pragma unroll
        for (int j = 0; j < 4; ++j) acc[i][j] = zero4;

    auto stage3 = [&](int slot, int koff) {
        unsigned short* base = &lds[slot][0];
        gload16((const unsigned short*)(pAg  + koff), base + dst);
        gload16((const unsigned short*)(pBg0 + koff), base + 4096 + dst);
        gload16((const unsigned short*)(pBg1 + koff), base + 8192 + dst);
    };
    auto rdA = [&](int slot, int mf) -> bf16x8 {
        return *reinterpret_cast<const bf16x8*>(
            (const char*)&lds[slot][0] + pbA + mf * 1024);
    };
    auto rdB = [&](int slot, int nf) -> bf16x8 {
        return *reinterpret_cast<const bf16x8*>(
            (const char*)&lds[slot][0] + 8192 + pbB + nf * 1024);
    };

    const int nt = ksub >> 5;
    stage3(0, 0);
    stage3(1, 64);
    vwait<3>();
    barrier_mem();
    int b0 = 0, b1 = 1, b2 = 2;
    for (int t = 0; t < nt; ++t) {
        const bool pf = (t + 2 < nt);
        if (pf) stage3(b2, (t + 2) * 64);
        bf16x8 bf0 = rdB(b0, 0), bf1 = rdB(b0, 1), bf2 = rdB(b0, 2), bf3 = rdB(b0, 3);
        bf16x8 a0 = rdA(b0, 0), a1 = rdA(b0, 1), a2 = rdA(b0, 2), a3 = rdA(b0, 3);
        __builtin_amdgcn_s_setprio(1);
        acc[0][0] = __builtin_amdgcn_mfma_f32_16x16x32_bf16(a0, bf0, acc[0][0], 0, 0, 0);
        acc[0][1] = __builtin_amdgcn_mfma_f32_16x16x32_bf16(a0, bf1, acc[0][1], 0, 0, 0);
        acc[0][2] = __builtin_amdgcn_mfma_f32_16x16x32_bf16(a0, bf2, acc[0][2], 0, 0, 0);
        acc[0][3] = __builtin_amdgcn_mfma_f32_16x16x32_bf16(a0, bf3, acc[0][3], 0, 0, 0);
        acc[1][0] = __builtin_amdgcn_mfma_f32_16x16x32_bf16(a1, bf0, acc[1][0], 0, 0, 0);
        acc[1][1] = __builtin_amdgcn_mfma_f32_16x16x32_bf16(a1, bf1, acc[1][1], 0, 0, 0);
        acc[1][2] = __builtin_amdgcn_mfma_f32_16x16x32_bf16(a1, bf2, acc[1][2], 0, 0, 0);
        acc[1][3] = __builtin_amdgcn_mfma_f32_16x16x32_bf16(a1, bf3, acc[1][3], 0, 0, 0);
        acc[2][0] = __builtin_amdgcn_mfma_f32_16x16x32_bf16(a2, bf0, acc[2][0], 0, 0, 0);
        acc[2][1] = __builtin_amdgcn_mfma_f32_16x16x32_bf16(a2, bf1, acc[2][1], 0, 0, 0);
        acc[2][2] = __builtin_amdgcn_mfma_f32_16x16x32_bf16(a2, bf2, acc[2][2], 0, 0, 0);
        acc[2][3] = __builtin_amdgcn_mfma_f32_16x16x32_bf16(a2, bf3, acc[2][3], 0, 0, 0);
        acc[3][0] = __builtin_amdgcn_mfma_f32_16x16x32_bf16(a3, bf0, acc[3][0], 0, 0, 0);
        acc[3][1] = __builtin_amdgcn_mfma_f32_16x16x32_bf16(a3, bf1, acc[3][1], 0, 0, 0);
        acc[3][2] = __builtin_amdgcn_mfma_f32_16x16x32_bf16(a3, bf2, acc[3][2], 0, 0, 0);
        acc[3][3] = __builtin_amdgcn_mfma_f32_16x16x32_bf16(a3, bf3, acc[3][3], 0, 0, 0);
        __builtin_amdgcn_s_setprio(0);
        if (t + 1 < nt) {
            if (pf) vwait<3>(); else vwait<0>();
            barrier_mem();
        }
        int tmp = b0; b0 = b1; b1 = b2; b2 = tmp;
    }

#pragma unroll
    for (int mf = 0; mf < 4; ++mf)
#pragma unroll
        for (int nf = 0; nf < 4; ++nf) {
            int col = n0 + wn * 64 + nf * 16 + lr;
            if (NEDGE && col >= N) continue;
            float bv = (BIAS && blockIdx.y == 0) ? bias[col] : 0.0f;
#pragma unroll
            for (int r = 0; r < 4; ++r) {
                int row = m0 + wm * 64 + mf * 16 + lg * 4 + r;
                float v = acc[mf][nf][r] + bv;
                if (ACT == 1) v = 0.5f * v * (1.0f + erff(v * 0.70710678118654752f));
                if (ATOMIC)
                    atomicAdd(reinterpret_cast<float*>(Cout) + (size_t)row * ldc + col, v);
                else if (OUTBF16)
                    reinterpret_cast<unsigned short*>(Cout)[(size_t)row * ldc + col] = f2bf(v);
                else
                    reinterpret_cast<float*>(Cout)[(size_t)row * ldc + col] = v;
            }
        }
}

// ---------------- V transpose: qkv v-part [t][d] -> vt[b][h][d][t] (bf16)
__global__ __launch_bounds__(256) void vtrans_kernel(
    const unsigned short* __restrict__ qkv, unsigned short* __restrict__ vt) {
    __shared__ unsigned short tile[32][33];
    int bh = blockIdx.z; int b = bh >> 4, h = bh & 15;
    int t0 = blockIdx.x * 32, d0 = blockIdx.y * 32;
    int tx = threadIdx.x, ty = threadIdx.y;  // (32,8)
#pragma unroll
    for (int i = 0; i < 4; ++i)
        tile[ty + i * 8][tx] =
            qkv[(size_t)(b * NT + t0 + ty + i * 8) * 3072 + 2048 + h * 64 + d0 + tx];
    __syncthreads();
#pragma unroll
    for (int i = 0; i < 4; ++i)
        vt[((size_t)(b * NH + h) * 64 + d0 + ty + i * 8) * NT + t0 + tx] = tile[tx][ty + i * 8];
}

// ---------------- causal flash attention, split-K over key tiles (2 splits).
// Writes UNNORMALIZED O-accum (bf16 partials) + per-row (m, l) in f32.
__global__ __launch_bounds__(64) void attn_kernel(
    const unsigned short* __restrict__ qkv, const unsigned short* __restrict__ vt,
    unsigned short* __restrict__ opart, float2* __restrict__ ml) {
    __shared__ unsigned short Vs[64][72];
    __shared__ unsigned short Ps[32][72];
    const int qt = blockIdx.x;
    const int h  = blockIdx.y;
    const int b  = blockIdx.z >> 1;
    const int sp = blockIdx.z & 1;
    const int lane = threadIdx.x;
    const int lr = lane & 15, lg = lane >> 4;

    const unsigned short* qbase = qkv + (size_t)(b * NT + qt * 32) * 3072 + h * 64;
    bf16x8 qf[2][2];
#pragma unroll
    for (int mf = 0; mf < 2; ++mf)
#pragma unroll
        for (int kc = 0; kc < 2; ++kc)
            qf[mf][kc] = *reinterpret_cast<const bf16x8*>(
                qbase + (size_t)(mf * 16 + lr) * 3072 + kc * 32 + lg * 8);

    const f32x4 zero4 = {0.0f, 0.0f, 0.0f, 0.0f};
    f32x4 oacc[2][4];
    float mrow[2][4], lsum[2][4];
#pragma unroll
    for (int mf = 0; mf < 2; ++mf) {
#pragma unroll
        for (int nf = 0; nf < 4; ++nf) oacc[mf][nf] = zero4;
#pragma unroll
        for (int r = 0; r < 4; ++r) { mrow[mf][r] = -INFINITY; lsum[mf][r] = 0.0f; }
    }

    const int qend = qt * 32 + 32;
    const int nkt = (qend + 63) >> 6;
    const int khalf = (nkt + 1) >> 1;
    const int kt0 = sp ? khalf : 0;
    const int kt1 = sp ? nkt : khalf;
    const unsigned short* kbase = qkv + (size_t)(b * NT) * 3072 + NC + h * 64;
    const unsigned short* vbase = vt + (size_t)((b * NH + h) * 64) * NT;

    for (int kt = kt0; kt < kt1; ++kt) {
        __syncthreads();
#pragma unroll
        for (int i = 0; i < 8; ++i) {
            int chunk = lane + i * 64;
            int d = chunk >> 3;
            int kk = (chunk & 7) * 8;
            *reinterpret_cast<bf16x8*>(&Vs[d][kk]) =
                *reinterpret_cast<const bf16x8*>(vbase + (size_t)d * NT + kt * 64 + kk);
        }
        f32x4 s[2][4];
#pragma unroll
        for (int mf = 0; mf < 2; ++mf)
#pragma unroll
            for (int jf = 0; jf < 4; ++jf) s[mf][jf] = zero4;
#pragma unroll
        for (int kc = 0; kc < 2; ++kc) {
            bf16x8 kf[4];
#pragma unroll
            for (int jf = 0; jf < 4; ++jf)
                kf[jf] = *reinterpret_cast<const bf16x8*>(
                    kbase + (size_t)(kt * 64 + jf * 16 + lr) * 3072 + kc * 32 + lg * 8);
#pragma unroll
            for (int mf = 0; mf < 2; ++mf)
#pragma unroll
                for (int jf = 0; jf < 4; ++jf)
                    s[mf][jf] = __builtin_amdgcn_mfma_f32_16x16x32_bf16(
                        qf[mf][kc], kf[jf], s[mf][jf], 0, 0, 0);
        }
        const bool lastt = (kt == nkt - 1);
#pragma unroll
        for (int mf = 0; mf < 2; ++mf) {
#pragma unroll
            for (int r = 0; r < 4; ++r) {
                int rowg = qt * 32 + mf * 16 + lg * 4 + r;
                float tmax = -INFINITY;
#pragma unroll
                for (int jf = 0; jf < 4; ++jf) {
                    float v = s[mf][jf][r] * 0.125f;
                    if (lastt) {
                        int colg = kt * 64 + jf * 16 + lr;
                        if (colg > rowg) v = -INFINITY;
                    }
                    s[mf][jf][r] = v;
                    tmax = fmaxf(tmax, v);
                }
                tmax = fmaxf(tmax, __shfl_xor(tmax, 1, 64));
                tmax = fmaxf(tmax, __shfl_xor(tmax, 2, 64));
                tmax = fmaxf(tmax, __shfl_xor(tmax, 4, 64));
                tmax = fmaxf(tmax, __shfl_xor(tmax, 8, 64));
                float mnew = fmaxf(mrow[mf][r], tmax);
                float corr = __expf(mrow[mf][r] - mnew);
                float ps = 0.0f;
#pragma unroll
                for (int jf = 0; jf < 4; ++jf) {
                    float p = __expf(s[mf][jf][r] - mnew);
                    s[mf][jf][r] = p;
                    ps += p;
                }
                ps += __shfl_xor(ps, 1, 64);
                ps += __shfl_xor(ps, 2, 64);
                ps += __shfl_xor(ps, 4, 64);
                ps += __shfl_xor(ps, 8, 64);
                lsum[mf][r] = lsum[mf][r] * corr + ps;
                mrow[mf][r] = mnew;
#pragma unroll
                for (int nf = 0; nf < 4; ++nf) oacc[mf][nf][r] *= corr;
            }
        }
#pragma unroll
        for (int mf = 0; mf < 2; ++mf)
#pragma unroll
            for (int jf = 0; jf < 4; ++jf)
#pragma unroll
                for (int r = 0; r < 4; ++r)
                    Ps[mf * 16 + lg * 4 + r][jf * 16 + lr] = f2bf(s[mf][jf][r]);
        __syncthreads();
#pragma unroll
        for (int kc = 0; kc < 2; ++kc) {
            bf16x8 pf[2], vf[4];
#pragma unroll
            for (int mf = 0; mf < 2; ++mf)
                pf[mf] = *reinterpret_cast<const bf16x8*>(&Ps[mf * 16 + lr][kc * 32 + lg * 8]);
#pragma unroll
            for (int nf = 0; nf < 4; ++nf)
                vf[nf] = *reinterpret_cast<const bf16x8*>(&Vs[nf * 16 + lr][kc * 32 + lg * 8]);
#pragma unroll
            for (int mf = 0; mf < 2; ++mf)
#pragma unroll
                for (int nf = 0; nf < 4; ++nf)
                    oacc[mf][nf] = __builtin_amdgcn_mfma_f32_16x16x32_bf16(
                        pf[mf], vf[nf], oacc[mf][nf], 0, 0, 0);
        }
    }

    const size_t rowbase = (size_t)sp * 2048 + b * NT + qt * 32;
    unsigned short* op = opart + rowbase * NC + h * 64;
#pragma unroll
    for (int mf = 0; mf < 2; ++mf)
#pragma unroll
        for (int nf = 0; nf < 4; ++nf)
#pragma unroll
            for (int r = 0; r < 4; ++r)
                op[(size_t)(mf * 16 + lg * 4 + r) * NC + nf * 16 + lr] = f2bf(oacc[mf][nf][r]);
    if (lr == 0) {
#pragma unroll
        for (int mf = 0; mf < 2; ++mf)
#pragma unroll
            for (int r = 0; r < 4; ++r)
                ml[(rowbase + mf * 16 + lg * 4 + r) * NH + h] =
                    make_float2(mrow[mf][r], lsum[mf][r]);
    }
}

// ---------------- combine 2 attention splits (bf16 partials) -> bf16 O
__global__ __launch_bounds__(256) void attn_combine_kernel(
    const unsigned short* __restrict__ opart, const float2* __restrict__ ml,
    unsigned short* __restrict__ o) {
    const int row = blockIdx.x;
    const int tid = threadIdx.x;
    const int h = tid >> 4;
    float2 a = ml[(size_t)row * NH + h];
    float2 c = ml[(size_t)(2048 + row) * NH + h];
    float m = fmaxf(a.x, c.x);
    float w0 = __expf(a.x - m), w1 = __expf(c.x - m);
    float inv = 1.0f / (a.y * w0 + c.y * w1);
    uint2 u0 = reinterpret_cast<const uint2*>(opart + (size_t)row * NC)[tid];
    uint2 u1 = reinterpret_cast<const uint2*>(opart + (size_t)(2048 + row) * NC)[tid];
    float o0x = bf2f((unsigned short)(u0.x & 0xFFFF)), o0y = bf2f((unsigned short)(u0.x >> 16));
    float o0z = bf2f((unsigned short)(u0.y & 0xFFFF)), o0w = bf2f((unsigned short)(u0.y >> 16));
    float o1x = bf2f((unsigned short)(u1.x & 0xFFFF)), o1y = bf2f((unsigned short)(u1.x >> 16));
    float o1z = bf2f((unsigned short)(u1.y & 0xFFFF)), o1w = bf2f((unsigned short)(u1.y >> 16));
    uint2 u;
    u.x = (unsigned)f2bf((o0x * w0 + o1x * w1) * inv) |
          ((unsigned)f2bf((o0y * w0 + o1y * w1) * inv) << 16);
    u.y = (unsigned)f2bf((o0z * w0 + o1z * w1) * inv) |
          ((unsigned)f2bf((o0w * w0 + o1w * w1) * inv) << 16);
    reinterpret_cast<uint2*>(o + (size_t)row * NC)[tid] = u;
}

extern "C" void kernel_launch(void* const* d_in, const int* in_sizes, int n_in,
                              void* d_out, int out_size, void* d_ws, size_t ws_size,
                              hipStream_t stream) {
    (void)in_sizes; (void)n_in; (void)out_size; (void)ws_size;
    const int*   idx    = (const int*)  d_in[0];
    const float* tok    = (const float*)d_in[1];
    const float* pos    = (const float*)d_in[2];
    const float* qkv_w  = (const float*)d_in[3];
    const float* qkv_b  = (const float*)d_in[4];
    const float* out_w  = (const float*)d_in[5];
    const float* out_b  = (const float*)d_in[6];
    const float* ln1_s  = (const float*)d_in[7];
    const float* ln1_b  = (const float*)d_in[8];
    const float* ln2_s  = (const float*)d_in[9];
    const float* ln2_b  = (const float*)d_in[10];
    const float* ffn_w1 = (const float*)d_in[11];
    const float* ffn_b1 = (const float*)d_in[12];
    const float* ffn_w2 = (const float*)d_in[13];
    const float* ffn_b2 = (const float*)d_in[14];
    const float* lnf_s  = (const float*)d_in[15];
    const float* lnf_b  = (const float*)d_in[16];

    char* p = (char*)d_ws;
    float* x              = (float*)p;          p += (size_t)NM * NC * 4;
    unsigned short* hbuf  = (unsigned short*)p; p += (size_t)NM * NC * 2;
    unsigned short* qkvb  = (unsigned short*)p; p += (size_t)NM * 3 * NC * 2;
    unsigned short* obuf  = (unsigned short*)p; p += (size_t)NM * NC * 2;
    unsigned short* gbuf  = (unsigned short*)p; p += (size_t)NM * NFF * 2;
    unsigned short* vtb   = (unsigned short*)p; p += (size_t)NB * NH * 64 * NT * 2;
    unsigned short* wq    = (unsigned short*)p; p += (size_t)3 * NC * NC * 2;
    unsigned short* wo    = (unsigned short*)p; p += (size_t)NC * NC * 2;
    unsigned short* w1    = (unsigned short*)p; p += (size_t)NC * NFF * 2;
    unsigned short* w2    = (unsigned short*)p; p += (size_t)NFF * NC * 2;
    unsigned short* temb  = (unsigned short*)p; p += (size_t)NV * NC * 2;
    unsigned short* opart = (unsigned short*)p; p += (size_t)2 * NM * NC * 2;
    float2* mlbuf         = (float2*)p;         p += (size_t)2 * NM * NH * 8;

    {
        size_t n4 = (size_t)NV * NC / 4;
        int blocks = (int)((n4 + 255) / 256);
        cvt_bf16_kernel<<<blocks, 256, 0, stream>>>(tok, temb, n4);
    }
    embed_kernel<<<NM, 256, 0, stream>>>(idx, tok, pos, x);

    for (int l = 0; l < NL; ++l) {
        wtrans4_kernel<<<12288, dim3(32, 8), 0, stream>>>(
            qkv_w + (size_t)l * NC * 3 * NC, out_w + (size_t)l * NC * NC,
            ffn_w1 + (size_t)l * NC * NFF, ffn_w2 + (size_t)l * NFF * NC,
            wq, wo, w1, w2);

        ln_kernel<<<NM, 256, 0, stream>>>(x, ln1_s + (size_t)l * NC, ln1_b + (size_t)l * NC, hbuf);
        gemm256_kernel<0, true, true, false, false><<<dim3(192), 512, 0, stream>>>(
            hbuf, wq, qkv_b + (size_t)l * 3 * NC, qkvb, 3 * NC, NC, 3 * NC, NC);
        vtrans_kernel<<<dim3(32, 2, 32), dim3(32, 8), 0, stream>>>(qkvb, vtb);
        attn_kernel<<<dim3(32, 16, 4), 64, 0, stream>>>(qkvb, vtb, opart, mlbuf);
        attn_combine_kernel<<<NM, 256, 0, stream>>>(opart, mlbuf, obuf);
        gemm_kernel<0, true, false, true><<<dim3(16, 8, 2), 256, 0, stream>>>(
            obuf, wo, out_b + (size_t)l * NC, x, NC, NC, NC, NC / 2);
        ln_kernel<<<NM, 256, 0, stream>>>(x, ln2_s + (size_t)l * NC, ln2_b + (size_t)l * NC, hbuf);
        gemm256_kernel<1, true, true, false, false><<<dim3(256), 512, 0, stream>>>(
            hbuf, w1, ffn_b1 + (size_t)l * NFF, gbuf, NFF, NC, NFF, NC);
        gemm256_kernel<0, true, false, false, true><<<dim3(64, 4), 512, 0, stream>>>(
            gbuf, w2, ffn_b2 + (size_t)l * NC, x, NC, NFF, NC, NFF / 4);
    }
    ln_kernel<<<NM, 256, 0, stream>>>(x, lnf_s, lnf_b, hbuf);
    // tied head: 128x256 tiles, grid = 16 M x 197 N = 3152 (%8==0)
    gemm256_kernel<0, false, false, true, false><<<dim3(16 * 197), 512, 0, stream>>>(
        hbuf, temb, nullptr, d_out, NV, NC, NV, NC);
}